// Round 6
// baseline (293.023 us; speedup 1.0000x reference)
//
#include <hip/hip_runtime.h>

// GCN forward: 2x GCNConv(64->64) + MLP(64->128->10), fp32, pull-based CSR.
// r6: agg2 folded into the MLP head kernel (block aggregates its own 64
// nodes into the XT LDS tile, then runs the tiled fc1/fc2). Deletes the
// separate k_agg dispatch + a 25.6MB global round-trip.

#define NFEAT 64

// ---- CSR build ----------------------------------------------------------

__global__ void k_hist(const int* __restrict__ row, int* __restrict__ cnt, int ne) {
    int i = blockIdx.x * blockDim.x + threadIdx.x;
    int st = gridDim.x * blockDim.x;
    for (; i < ne; i += st) atomicAdd(&cnt[row[i]], 1);
}

__global__ void k_scanA(const int* __restrict__ cnt, int* __restrict__ bsum, int n) {
    __shared__ int s[256];
    int tid = threadIdx.x;
    int i = blockIdx.x * 256 + tid;
    s[tid] = (i < n) ? cnt[i] : 0;
    __syncthreads();
    for (int d = 128; d > 0; d >>= 1) {
        if (tid < d) s[tid] += s[tid + d];
        __syncthreads();
    }
    if (tid == 0) bsum[blockIdx.x] = s[0];
}

__global__ void k_scanB(const int* __restrict__ bsum, int* __restrict__ bpre, int nb) {
    __shared__ int s[256];
    int tid = threadIdx.x;
    int v = (tid < nb) ? bsum[tid] : 0;
    s[tid] = v;
    __syncthreads();
    for (int d = 1; d < 256; d <<= 1) {
        int t = (tid >= d) ? s[tid - d] : 0;
        __syncthreads();
        s[tid] += t;
        __syncthreads();
    }
    if (tid < nb) bpre[tid] = s[tid] - v;  // exclusive
}

// exclusive per-element offsets + dis = rsqrt(1+deg)
__global__ void k_scanC(const int* __restrict__ cnt, const int* __restrict__ bpre,
                        int* __restrict__ off, float* __restrict__ dis, int n) {
    __shared__ int s[256];
    int tid = threadIdx.x;
    int i = blockIdx.x * 256 + tid;
    int v = (i < n) ? cnt[i] : 0;
    s[tid] = v;
    __syncthreads();
    for (int d = 1; d < 256; d <<= 1) {
        int t = (tid >= d) ? s[tid - d] : 0;
        __syncthreads();
        s[tid] += t;
        __syncthreads();
    }
    if (i < n) {
        off[i] = bpre[blockIdx.x] + s[tid] - v;
        dis[i] = rsqrtf(1.0f + (float)v);
    }
}

// slot = off[row]++ ; csr[slot] = {col, w} (plain 8B store; scattered writes
// cost a 64B line regardless). off[i] ends at segment END.
__global__ void k_fill(const int* __restrict__ row, const int* __restrict__ col,
                       const float* __restrict__ ew, const float* __restrict__ dis,
                       int* __restrict__ off, int2* __restrict__ csr, int ne) {
    int i = blockIdx.x * blockDim.x + threadIdx.x;
    if (i >= ne) return;
    int r = row[i], c = col[i];
    float w = dis[r] * ew[i] * dis[c];
    int slot = atomicAdd(&off[r], 1);
    csr[slot] = make_int2(c, __float_as_int(w));
}

// ---- dense: Y[nrows,64] = X @ W[64,64] -----------------------------------

__global__ __launch_bounds__(256) void k_gemm64(const float* __restrict__ X,
                                                const float* __restrict__ W,
                                                float* __restrict__ Y, int nrows) {
    __shared__ float Wl[64 * 64];   // [k][f]
    __shared__ float XT[64 * 68];   // [k][r], padded
    int tid = threadIdx.x;
    int r0 = blockIdx.x * 64;
    for (int i = tid; i < 64 * 64; i += 256) Wl[i] = W[i];
    for (int i = tid; i < 64 * 64; i += 256) {
        int r = i >> 6, k = i & 63;
        int rr = r0 + r;
        XT[k * 68 + r] = (rr < nrows) ? X[(size_t)r0 * 64 + i] : 0.f;
    }
    __syncthreads();
    int f4 = (tid & 15) * 4;
    int r4 = (tid >> 4) * 4;
    float acc[4][4];
#pragma unroll
    for (int i = 0; i < 4; ++i)
#pragma unroll
        for (int j = 0; j < 4; ++j) acc[i][j] = 0.f;
#pragma unroll 8
    for (int k = 0; k < 64; ++k) {
        float4 w = *(const float4*)&Wl[k * 64 + f4];
        float4 xv = *(const float4*)&XT[k * 68 + r4];
        float xs[4] = {xv.x, xv.y, xv.z, xv.w};
        float ws[4] = {w.x, w.y, w.z, w.w};
#pragma unroll
        for (int i = 0; i < 4; ++i)
#pragma unroll
            for (int j = 0; j < 4; ++j) acc[i][j] = fmaf(xs[i], ws[j], acc[i][j]);
    }
#pragma unroll
    for (int i = 0; i < 4; ++i) {
        int rr = r0 + r4 + i;
        if (rr < nrows) {
            float4 o = make_float4(acc[i][0], acc[i][1], acc[i][2], acc[i][3]);
            *(float4*)&Y[(size_t)rr * 64 + f4] = o;
        }
    }
}

// ---- agg core: returns aggregated quad (ALL lanes valid after reduce) ----

__device__ __forceinline__ float4 agg_row(const int* off_end, const int* cnt,
                                          const int2* csr, const float* H,
                                          int node, int sub, int q4) {
    int endv = off_end[node];
    int s = endv - cnt[node];
    float4 acc = make_float4(0.f, 0.f, 0.f, 0.f);
    int e = s + sub;
    for (; e + 4 < endv; e += 8) {
        int2 p0 = csr[e];
        int2 p1 = csr[e + 4];
        float w0 = __int_as_float(p0.y);
        float w1 = __int_as_float(p1.y);
        float4 h0 = *(const float4*)&H[(size_t)p0.x * 64 + q4];
        float4 h1 = *(const float4*)&H[(size_t)p1.x * 64 + q4];
        acc.x = fmaf(w0, h0.x, acc.x);
        acc.y = fmaf(w0, h0.y, acc.y);
        acc.z = fmaf(w0, h0.z, acc.z);
        acc.w = fmaf(w0, h0.w, acc.w);
        acc.x = fmaf(w1, h1.x, acc.x);
        acc.y = fmaf(w1, h1.y, acc.y);
        acc.z = fmaf(w1, h1.z, acc.z);
        acc.w = fmaf(w1, h1.w, acc.w);
    }
    if (e < endv) {
        int2 p = csr[e];
        float w = __int_as_float(p.y);
        float4 h = *(const float4*)&H[(size_t)p.x * 64 + q4];
        acc.x = fmaf(w, h.x, acc.x);
        acc.y = fmaf(w, h.y, acc.y);
        acc.z = fmaf(w, h.z, acc.z);
        acc.w = fmaf(w, h.w, acc.w);
    }
#pragma unroll
    for (int m = 16; m <= 32; m <<= 1) {
        acc.x += __shfl_xor(acc.x, m, 64);
        acc.y += __shfl_xor(acc.y, m, 64);
        acc.z += __shfl_xor(acc.z, m, 64);
        acc.w += __shfl_xor(acc.w, m, 64);
    }
    return acc;  // every lane: sum over in-edges for quad (lane&15)
}

// ---- fused agg1 + layer2 transform: H2 = relu(sym-agg(H1)+b1) @ W2 -------

__global__ __launch_bounds__(256) void k_agg_fused(const int* __restrict__ off_end,
                                                   const int* __restrict__ cnt,
                                                   const float* __restrict__ dis,
                                                   const int2* __restrict__ csr,
                                                   const float* __restrict__ H1,
                                                   const float* __restrict__ b1,
                                                   const float* __restrict__ W2,
                                                   float* __restrict__ H2, int n) {
    __shared__ float W2l[64 * 64];   // [k][f] 16KB
    __shared__ float pbuf[4][64];    // per-wave row buffer
    int tid = threadIdx.x;
    for (int i = tid; i < 64 * 64; i += 256) W2l[i] = W2[i];
    __syncthreads();
    int l = tid & 63;
    int wv = tid >> 6;
    int sub = l >> 4;
    int q4 = (l & 15) * 4;
    int nwaves = (gridDim.x * blockDim.x) >> 6;
    for (int node = (blockIdx.x * blockDim.x + tid) >> 6; node < n; node += nwaves) {
        float4 acc = agg_row(off_end, cnt, csr, H1, node, sub, q4);
        float d = dis[node];
        float d2 = d * d;
        float4 hs = *(const float4*)&H1[(size_t)node * 64 + q4];
        float4 bq = *(const float4*)&b1[q4];
        float4 p;
        p.x = fmaxf(fmaf(d2, hs.x, acc.x) + bq.x, 0.f);
        p.y = fmaxf(fmaf(d2, hs.y, acc.y) + bq.y, 0.f);
        p.z = fmaxf(fmaf(d2, hs.z, acc.z) + bq.z, 0.f);
        p.w = fmaxf(fmaf(d2, hs.w, acc.w) + bq.w, 0.f);
        if (sub == 0) *(float4*)&pbuf[wv][q4] = p;
        asm volatile("s_waitcnt lgkmcnt(0)" ::: "memory");
        float sum = 0.f;
#pragma unroll
        for (int q = 0; q < 16; ++q) {
            float4 v = *(const float4*)&pbuf[wv][q * 4];
            sum = fmaf(v.x, W2l[(q * 4 + 0) * 64 + l], sum);
            sum = fmaf(v.y, W2l[(q * 4 + 1) * 64 + l], sum);
            sum = fmaf(v.z, W2l[(q * 4 + 2) * 64 + l], sum);
            sum = fmaf(v.w, W2l[(q * 4 + 3) * 64 + l], sum);
        }
        asm volatile("s_waitcnt lgkmcnt(0)" ::: "memory");
        H2[(size_t)node * 64 + l] = sum;
    }
}

// ---- fused agg2 + MLP head ----------------------------------------------
// Block owns 64 nodes: 4 waves each pull-aggregate 16 nodes (wave-per-node)
// depositing conv2 rows (+b2) transposed into XT; then tiled fc1/fc2.

__global__ __launch_bounds__(256, 4) void k_agg_mlp(const int* __restrict__ off_end,
                                                    const int* __restrict__ cnt,
                                                    const float* __restrict__ dis,
                                                    const int2* __restrict__ csr,
                                                    const float* __restrict__ H2,
                                                    const float* __restrict__ b2,
                                                    const float* __restrict__ fc1w,
                                                    const float* __restrict__ fc1b,
                                                    const float* __restrict__ fc2w,
                                                    const float* __restrict__ fc2b,
                                                    float* __restrict__ out, int n) {
    __shared__ float XT[64 * 68];    // [k][r] conv2-output tile (+b2)
    __shared__ float Wh[64 * 64];    // one 64-col half of fc1w
    __shared__ float W2l[128 * 10];
    __shared__ float b1l[128];
    __shared__ float b2c[16];
    __shared__ float b2in[64];
    int tid = threadIdx.x;
    int r0 = blockIdx.x * 64;
    // stage weights/biases (fc1 half 0 now; half 1 later)
    for (int i = tid; i < 64 * 64; i += 256)
        Wh[i] = fc1w[(i >> 6) * 128 + (i & 63)];
    for (int i = tid; i < 128 * 10; i += 256) W2l[i] = fc2w[i];
    if (tid < 128) b1l[tid] = fc1b[tid];
    if (tid < 10) b2c[tid] = fc2b[tid];
    if (tid < 64) b2in[tid] = b2[tid];

    // aggregate: wave wv handles local rows wv*16..wv*16+15
    int l = tid & 63;
    int wv = tid >> 6;
    int sub = l >> 4;
    int q4 = (l & 15) * 4;
    for (int t = 0; t < 16; ++t) {
        int r = wv * 16 + t;
        int node = r0 + r;
        if (node < n) {
            float4 acc = agg_row(off_end, cnt, csr, H2, node, sub, q4);
            if (sub == 0) {
                float d = dis[node];
                float d2 = d * d;
                float4 hs = *(const float4*)&H2[(size_t)node * 64 + q4];
                XT[(q4 + 0) * 68 + r] = fmaf(d2, hs.x, acc.x) + b2in[q4 + 0];
                XT[(q4 + 1) * 68 + r] = fmaf(d2, hs.y, acc.y) + b2in[q4 + 1];
                XT[(q4 + 2) * 68 + r] = fmaf(d2, hs.z, acc.z) + b2in[q4 + 2];
                XT[(q4 + 3) * 68 + r] = fmaf(d2, hs.w, acc.w) + b2in[q4 + 3];
            }
        } else if (sub == 0) {
            XT[(q4 + 0) * 68 + r] = 0.f;
            XT[(q4 + 1) * 68 + r] = 0.f;
            XT[(q4 + 2) * 68 + r] = 0.f;
            XT[(q4 + 3) * 68 + r] = 0.f;
        }
    }
    __syncthreads();

    int f4 = (tid & 15) * 4;
    int r4 = (tid >> 4) * 4;
    float pacc[4][10];
#pragma unroll
    for (int i = 0; i < 4; ++i)
#pragma unroll
        for (int c = 0; c < 10; ++c) pacc[i][c] = 0.f;

#pragma unroll
    for (int h = 0; h < 2; ++h) {
        if (h == 1) {
            __syncthreads();
            for (int i = tid; i < 64 * 64; i += 256)
                Wh[i] = fc1w[(i >> 6) * 128 + 64 + (i & 63)];
            __syncthreads();
        }
        float acc[4][4];
#pragma unroll
        for (int i = 0; i < 4; ++i)
#pragma unroll
            for (int j = 0; j < 4; ++j) acc[i][j] = 0.f;
#pragma unroll 8
        for (int k = 0; k < 64; ++k) {
            float4 xv = *(const float4*)&XT[k * 68 + r4];
            float4 wv4 = *(const float4*)&Wh[k * 64 + f4];
            float xs[4] = {xv.x, xv.y, xv.z, xv.w};
            float ws[4] = {wv4.x, wv4.y, wv4.z, wv4.w};
#pragma unroll
            for (int i = 0; i < 4; ++i)
#pragma unroll
                for (int j = 0; j < 4; ++j) acc[i][j] = fmaf(xs[i], ws[j], acc[i][j]);
        }
#pragma unroll
        for (int jj = 0; jj < 4; ++jj) {
            int jcol = h * 64 + f4 + jj;
            float w2r[10];
#pragma unroll
            for (int c = 0; c < 10; ++c) w2r[c] = W2l[jcol * 10 + c];
            float bj = b1l[jcol];
#pragma unroll
            for (int i = 0; i < 4; ++i) {
                float pv = fmaxf(acc[i][jj] + bj, 0.f);
#pragma unroll
                for (int c = 0; c < 10; ++c) pacc[i][c] = fmaf(pv, w2r[c], pacc[i][c]);
            }
        }
    }
#pragma unroll
    for (int i = 0; i < 4; ++i)
#pragma unroll
        for (int c = 0; c < 10; ++c) {
            float v = pacc[i][c];
            v += __shfl_xor(v, 1, 64);
            v += __shfl_xor(v, 2, 64);
            v += __shfl_xor(v, 4, 64);
            v += __shfl_xor(v, 8, 64);
            pacc[i][c] = v;
        }
    if ((tid & 15) == 0) {
#pragma unroll
        for (int i = 0; i < 4; ++i) {
            int rr = r0 + r4 + i;
            if (rr < n) {
#pragma unroll
                for (int c = 0; c < 10; ++c)
                    out[(size_t)rr * 10 + c] = pacc[i][c] + b2c[c];
            }
        }
    }
}

// --------------------------------------------------------------------------

extern "C" void kernel_launch(void* const* d_in, const int* in_sizes, int n_in,
                              void* d_out, int out_size, void* d_ws, size_t ws_size,
                              hipStream_t stream) {
    const float* x     = (const float*)d_in[0];
    const int*   eidx  = (const int*)d_in[1];
    const float* eattr = (const float*)d_in[2];
    const float* W1    = (const float*)d_in[3];
    const float* b1    = (const float*)d_in[4];
    const float* W2    = (const float*)d_in[5];
    const float* b2    = (const float*)d_in[6];
    const float* fc1w  = (const float*)d_in[7];
    const float* fc1b  = (const float*)d_in[8];
    const float* fc2w  = (const float*)d_in[9];
    const float* fc2b  = (const float*)d_in[10];
    float* out = (float*)d_out;

    const int N = in_sizes[0] / NFEAT;   // 50000
    const int E = in_sizes[2];           // 800000
    const int* row = eidx;
    const int* col = eidx + E;

    // workspace layout
    int*   icnt = (int*)d_ws;                  // N (padded 50176)
    int*   off  = icnt + 50176;                // N
    float* dis  = (float*)(off + 50176);       // N
    int*   bsum = (int*)(dis + 50176);         // 256
    int*   bpre = bsum + 256;                  // 256
    int2*  csr  = (int2*)(bpre + 256);         // E x 8B
    float* H    = (float*)(csr + E);           // N*64
    float* H2   = H + (size_t)N * 64;          // N*64

    const int TB = 256;
    int gN = (N + TB - 1) / TB;                // 196
    int gG = (N + 63) / 64;                    // 782
    int gE1 = (E + TB - 1) / TB;               // 3125
    int nb = gN;

    hipMemsetAsync(icnt, 0, (size_t)N * sizeof(int), stream);
    k_hist<<<1024, TB, 0, stream>>>(row, icnt, E);
    k_scanA<<<nb, TB, 0, stream>>>(icnt, bsum, N);
    k_scanB<<<1, TB, 0, stream>>>(bsum, bpre, nb);
    k_scanC<<<nb, TB, 0, stream>>>(icnt, bpre, off, dis, N);
    k_fill<<<gE1, TB, 0, stream>>>(row, col, eattr, dis, off, csr, E);

    // layer 1 GEMM
    k_gemm64<<<gG, TB, 0, stream>>>(x, W1, H, N);
    // agg1 + relu(.+b1)@W2 fused -> H2 (layer-2 features)
    k_agg_fused<<<2048, TB, 0, stream>>>(off, icnt, dis, csr, H, b1, W2, H2, N);
    // agg2 + full MLP head fused -> out
    k_agg_mlp<<<gG, TB, 0, stream>>>(off, icnt, dis, csr, H2, b2,
                                     fc1w, fc1b, fc2w, fc2b, out, N);
}

// Round 7
// 287.390 us; speedup vs baseline: 1.0196x; 1.0196x over previous
//
#include <hip/hip_runtime.h>

// GCN forward: 2x GCNConv(64->64) + MLP(64->128->10), fp32, pull-based CSR.
// r7: revert r6's agg2+mlp fusion (gather needs one-wave-per-node parallelism;
// 782-block fusion collapsed latency hiding). r5 structure + (1) compiler-only
// fences in k_agg_fused (same-wave LDS is in-order; drop lgkmcnt(0) drains),
// (2) k_mlp prefetches fc1w half-1 into registers under half-0 compute.

#define NFEAT 64

// ---- CSR build ----------------------------------------------------------

__global__ void k_hist(const int* __restrict__ row, int* __restrict__ cnt, int ne) {
    int i = blockIdx.x * blockDim.x + threadIdx.x;
    int st = gridDim.x * blockDim.x;
    for (; i < ne; i += st) atomicAdd(&cnt[row[i]], 1);
}

__global__ void k_scanA(const int* __restrict__ cnt, int* __restrict__ bsum, int n) {
    __shared__ int s[256];
    int tid = threadIdx.x;
    int i = blockIdx.x * 256 + tid;
    s[tid] = (i < n) ? cnt[i] : 0;
    __syncthreads();
    for (int d = 128; d > 0; d >>= 1) {
        if (tid < d) s[tid] += s[tid + d];
        __syncthreads();
    }
    if (tid == 0) bsum[blockIdx.x] = s[0];
}

__global__ void k_scanB(const int* __restrict__ bsum, int* __restrict__ bpre, int nb) {
    __shared__ int s[256];
    int tid = threadIdx.x;
    int v = (tid < nb) ? bsum[tid] : 0;
    s[tid] = v;
    __syncthreads();
    for (int d = 1; d < 256; d <<= 1) {
        int t = (tid >= d) ? s[tid - d] : 0;
        __syncthreads();
        s[tid] += t;
        __syncthreads();
    }
    if (tid < nb) bpre[tid] = s[tid] - v;  // exclusive
}

// exclusive per-element offsets + dis = rsqrt(1+deg)
__global__ void k_scanC(const int* __restrict__ cnt, const int* __restrict__ bpre,
                        int* __restrict__ off, float* __restrict__ dis, int n) {
    __shared__ int s[256];
    int tid = threadIdx.x;
    int i = blockIdx.x * 256 + tid;
    int v = (i < n) ? cnt[i] : 0;
    s[tid] = v;
    __syncthreads();
    for (int d = 1; d < 256; d <<= 1) {
        int t = (tid >= d) ? s[tid - d] : 0;
        __syncthreads();
        s[tid] += t;
        __syncthreads();
    }
    if (i < n) {
        off[i] = bpre[blockIdx.x] + s[tid] - v;
        dis[i] = rsqrtf(1.0f + (float)v);
    }
}

// slot = off[row]++ ; csr[slot] = {col, w} (plain 8B store; scattered writes
// cost a 64B line regardless of store width/atomicity). off ends at seg END.
__global__ void k_fill(const int* __restrict__ row, const int* __restrict__ col,
                       const float* __restrict__ ew, const float* __restrict__ dis,
                       int* __restrict__ off, int2* __restrict__ csr, int ne) {
    int i = blockIdx.x * blockDim.x + threadIdx.x;
    if (i >= ne) return;
    int r = row[i], c = col[i];
    float w = dis[r] * ew[i] * dis[c];
    int slot = atomicAdd(&off[r], 1);
    csr[slot] = make_int2(c, __float_as_int(w));
}

// ---- dense: Y[nrows,64] = X @ W[64,64] -----------------------------------

__global__ __launch_bounds__(256) void k_gemm64(const float* __restrict__ X,
                                                const float* __restrict__ W,
                                                float* __restrict__ Y, int nrows) {
    __shared__ float Wl[64 * 64];   // [k][f]
    __shared__ float XT[64 * 68];   // [k][r], padded
    int tid = threadIdx.x;
    int r0 = blockIdx.x * 64;
    for (int i = tid; i < 64 * 64; i += 256) Wl[i] = W[i];
    for (int i = tid; i < 64 * 64; i += 256) {
        int r = i >> 6, k = i & 63;
        int rr = r0 + r;
        XT[k * 68 + r] = (rr < nrows) ? X[(size_t)r0 * 64 + i] : 0.f;
    }
    __syncthreads();
    int f4 = (tid & 15) * 4;
    int r4 = (tid >> 4) * 4;
    float acc[4][4];
#pragma unroll
    for (int i = 0; i < 4; ++i)
#pragma unroll
        for (int j = 0; j < 4; ++j) acc[i][j] = 0.f;
#pragma unroll 8
    for (int k = 0; k < 64; ++k) {
        float4 w = *(const float4*)&Wl[k * 64 + f4];
        float4 xv = *(const float4*)&XT[k * 68 + r4];
        float xs[4] = {xv.x, xv.y, xv.z, xv.w};
        float ws[4] = {w.x, w.y, w.z, w.w};
#pragma unroll
        for (int i = 0; i < 4; ++i)
#pragma unroll
            for (int j = 0; j < 4; ++j) acc[i][j] = fmaf(xs[i], ws[j], acc[i][j]);
    }
#pragma unroll
    for (int i = 0; i < 4; ++i) {
        int rr = r0 + r4 + i;
        if (rr < nrows) {
            float4 o = make_float4(acc[i][0], acc[i][1], acc[i][2], acc[i][3]);
            *(float4*)&Y[(size_t)rr * 64 + f4] = o;
        }
    }
}

// ---- agg core: returns aggregated quad (ALL lanes valid after reduce) ----

__device__ __forceinline__ float4 agg_row(const int* off_end, const int* cnt,
                                          const int2* csr, const float* H,
                                          int node, int sub, int q4) {
    int endv = off_end[node];
    int s = endv - cnt[node];
    float4 acc = make_float4(0.f, 0.f, 0.f, 0.f);
    int e = s + sub;
    for (; e + 4 < endv; e += 8) {
        int2 p0 = csr[e];
        int2 p1 = csr[e + 4];
        float w0 = __int_as_float(p0.y);
        float w1 = __int_as_float(p1.y);
        float4 h0 = *(const float4*)&H[(size_t)p0.x * 64 + q4];
        float4 h1 = *(const float4*)&H[(size_t)p1.x * 64 + q4];
        acc.x = fmaf(w0, h0.x, acc.x);
        acc.y = fmaf(w0, h0.y, acc.y);
        acc.z = fmaf(w0, h0.z, acc.z);
        acc.w = fmaf(w0, h0.w, acc.w);
        acc.x = fmaf(w1, h1.x, acc.x);
        acc.y = fmaf(w1, h1.y, acc.y);
        acc.z = fmaf(w1, h1.z, acc.z);
        acc.w = fmaf(w1, h1.w, acc.w);
    }
    if (e < endv) {
        int2 p = csr[e];
        float w = __int_as_float(p.y);
        float4 h = *(const float4*)&H[(size_t)p.x * 64 + q4];
        acc.x = fmaf(w, h.x, acc.x);
        acc.y = fmaf(w, h.y, acc.y);
        acc.z = fmaf(w, h.z, acc.z);
        acc.w = fmaf(w, h.w, acc.w);
    }
#pragma unroll
    for (int m = 16; m <= 32; m <<= 1) {
        acc.x += __shfl_xor(acc.x, m, 64);
        acc.y += __shfl_xor(acc.y, m, 64);
        acc.z += __shfl_xor(acc.z, m, 64);
        acc.w += __shfl_xor(acc.w, m, 64);
    }
    return acc;  // every lane: sum over in-edges for quad (lane&15)
}

// ---- plain agg (layer 2): AGG[i] = dis^2*H[i] + sum w*H[c] ---------------

__global__ __launch_bounds__(256) void k_agg(const int* __restrict__ off_end,
                                             const int* __restrict__ cnt,
                                             const float* __restrict__ dis,
                                             const int2* __restrict__ csr,
                                             const float* __restrict__ H,
                                             float* __restrict__ AGG, int n) {
    int l = threadIdx.x & 63;
    int node = (blockIdx.x * blockDim.x + threadIdx.x) >> 6;
    if (node >= n) return;
    int sub = l >> 4;
    int q4 = (l & 15) * 4;
    float4 acc = agg_row(off_end, cnt, csr, H, node, sub, q4);
    if (sub == 0) {
        float d = dis[node];
        float d2 = d * d;
        float4 hs = *(const float4*)&H[(size_t)node * 64 + q4];
        acc.x = fmaf(d2, hs.x, acc.x);
        acc.y = fmaf(d2, hs.y, acc.y);
        acc.z = fmaf(d2, hs.z, acc.z);
        acc.w = fmaf(d2, hs.w, acc.w);
        *(float4*)&AGG[(size_t)node * 64 + q4] = acc;
    }
}

// ---- fused agg1 + layer2 transform: H2 = relu(sym-agg(H1)+b1) @ W2 -------
// Per node: agg row (all lanes), +self +b1, relu, stash 64-float row in a
// per-wave LDS buffer, then lane f computes row @ W2[:,f] from LDS W2.
// Same-wave LDS ops are in-order on CDNA: only compiler barriers needed for
// the pbuf handoff (no lgkmcnt(0) drain -> gathers stay in flight).

__global__ __launch_bounds__(256) void k_agg_fused(const int* __restrict__ off_end,
                                                   const int* __restrict__ cnt,
                                                   const float* __restrict__ dis,
                                                   const int2* __restrict__ csr,
                                                   const float* __restrict__ H1,
                                                   const float* __restrict__ b1,
                                                   const float* __restrict__ W2,
                                                   float* __restrict__ H2, int n) {
    __shared__ float W2l[64 * 64];   // [k][f] 16KB
    __shared__ float pbuf[4][64];    // per-wave row buffer
    int tid = threadIdx.x;
    for (int i = tid; i < 64 * 64; i += 256) W2l[i] = W2[i];
    __syncthreads();
    int l = tid & 63;
    int wv = tid >> 6;
    int sub = l >> 4;
    int q4 = (l & 15) * 4;
    int nwaves = (gridDim.x * blockDim.x) >> 6;
    for (int node = (blockIdx.x * blockDim.x + tid) >> 6; node < n; node += nwaves) {
        float4 acc = agg_row(off_end, cnt, csr, H1, node, sub, q4);
        float d = dis[node];
        float d2 = d * d;
        float4 hs = *(const float4*)&H1[(size_t)node * 64 + q4];
        float4 bq = *(const float4*)&b1[q4];
        float4 p;
        p.x = fmaxf(fmaf(d2, hs.x, acc.x) + bq.x, 0.f);
        p.y = fmaxf(fmaf(d2, hs.y, acc.y) + bq.y, 0.f);
        p.z = fmaxf(fmaf(d2, hs.z, acc.z) + bq.z, 0.f);
        p.w = fmaxf(fmaf(d2, hs.w, acc.w) + bq.w, 0.f);
        if (sub == 0) *(float4*)&pbuf[wv][q4] = p;
        asm volatile("" ::: "memory");  // compiler fence; HW LDS pipe is in-order per wave
        float sum = 0.f;
#pragma unroll
        for (int q = 0; q < 16; ++q) {
            float4 v = *(const float4*)&pbuf[wv][q * 4];
            sum = fmaf(v.x, W2l[(q * 4 + 0) * 64 + l], sum);
            sum = fmaf(v.y, W2l[(q * 4 + 1) * 64 + l], sum);
            sum = fmaf(v.z, W2l[(q * 4 + 2) * 64 + l], sum);
            sum = fmaf(v.w, W2l[(q * 4 + 3) * 64 + l], sum);
        }
        asm volatile("" ::: "memory");  // reads ordered before next iter's write
        H2[(size_t)node * 64 + l] = sum;
    }
}

// ---- fused MLP head: out = relu((AGG+b2)@fc1 + fc1b) @ fc2 + fc2b --------

__global__ __launch_bounds__(256, 4) void k_mlp(const float* __restrict__ AGG,
                                                const float* __restrict__ b2,
                                                const float* __restrict__ fc1w,
                                                const float* __restrict__ fc1b,
                                                const float* __restrict__ fc2w,
                                                const float* __restrict__ fc2b,
                                                float* __restrict__ out, int n) {
    __shared__ float XT[64 * 68];    // [k][r] transposed input tile
    __shared__ float Wh[64 * 64];    // one 64-col half of fc1w
    __shared__ float W2l[128 * 10];
    __shared__ float b1l[128];
    __shared__ float b2c[16];
    int tid = threadIdx.x;
    int r0 = blockIdx.x * 64;
    for (int i = tid; i < 64 * 64; i += 256) {
        int r = i >> 6, k = i & 63;
        int rr = r0 + r;
        float v = 0.f;
        if (rr < n) v = AGG[(size_t)r0 * 64 + i] + b2[k];
        XT[k * 68 + r] = v;
    }
    for (int i = tid; i < 64 * 64; i += 256)
        Wh[i] = fc1w[(i >> 6) * 128 + (i & 63)];
    for (int i = tid; i < 128 * 10; i += 256) W2l[i] = fc2w[i];
    if (tid < 128) b1l[tid] = fc1b[tid];
    if (tid < 10) b2c[tid] = fc2b[tid];
    // prefetch fc1w half-1 into regs; loads retire under half-0 compute
    float wreg[16];
#pragma unroll
    for (int i = 0; i < 16; ++i) {
        int idx = i * 256 + tid;
        wreg[i] = fc1w[(idx >> 6) * 128 + 64 + (idx & 63)];
    }
    __syncthreads();

    int f4 = (tid & 15) * 4;
    int r4 = (tid >> 4) * 4;
    float pacc[4][10];
#pragma unroll
    for (int i = 0; i < 4; ++i)
#pragma unroll
        for (int c = 0; c < 10; ++c) pacc[i][c] = 0.f;

#pragma unroll
    for (int h = 0; h < 2; ++h) {
        if (h == 1) {
            __syncthreads();
#pragma unroll
            for (int i = 0; i < 16; ++i) Wh[i * 256 + tid] = wreg[i];
            __syncthreads();
        }
        float acc[4][4];
#pragma unroll
        for (int i = 0; i < 4; ++i)
#pragma unroll
            for (int j = 0; j < 4; ++j) acc[i][j] = 0.f;
#pragma unroll 8
        for (int k = 0; k < 64; ++k) {
            float4 xv = *(const float4*)&XT[k * 68 + r4];
            float4 wv = *(const float4*)&Wh[k * 64 + f4];
            float xs[4] = {xv.x, xv.y, xv.z, xv.w};
            float ws[4] = {wv.x, wv.y, wv.z, wv.w};
#pragma unroll
            for (int i = 0; i < 4; ++i)
#pragma unroll
                for (int j = 0; j < 4; ++j) acc[i][j] = fmaf(xs[i], ws[j], acc[i][j]);
        }
#pragma unroll
        for (int jj = 0; jj < 4; ++jj) {
            int jcol = h * 64 + f4 + jj;
            float w2r[10];
#pragma unroll
            for (int c = 0; c < 10; ++c) w2r[c] = W2l[jcol * 10 + c];
            float bj = b1l[jcol];
#pragma unroll
            for (int i = 0; i < 4; ++i) {
                float pv = fmaxf(acc[i][jj] + bj, 0.f);
#pragma unroll
                for (int c = 0; c < 10; ++c) pacc[i][c] = fmaf(pv, w2r[c], pacc[i][c]);
            }
        }
    }
#pragma unroll
    for (int i = 0; i < 4; ++i)
#pragma unroll
        for (int c = 0; c < 10; ++c) {
            float v = pacc[i][c];
            v += __shfl_xor(v, 1, 64);
            v += __shfl_xor(v, 2, 64);
            v += __shfl_xor(v, 4, 64);
            v += __shfl_xor(v, 8, 64);
            pacc[i][c] = v;
        }
    if ((tid & 15) == 0) {
#pragma unroll
        for (int i = 0; i < 4; ++i) {
            int rr = r0 + r4 + i;
            if (rr < n) {
#pragma unroll
                for (int c = 0; c < 10; ++c)
                    out[(size_t)rr * 10 + c] = pacc[i][c] + b2c[c];
            }
        }
    }
}

// --------------------------------------------------------------------------

extern "C" void kernel_launch(void* const* d_in, const int* in_sizes, int n_in,
                              void* d_out, int out_size, void* d_ws, size_t ws_size,
                              hipStream_t stream) {
    const float* x     = (const float*)d_in[0];
    const int*   eidx  = (const int*)d_in[1];
    const float* eattr = (const float*)d_in[2];
    const float* W1    = (const float*)d_in[3];
    const float* b1    = (const float*)d_in[4];
    const float* W2    = (const float*)d_in[5];
    const float* b2    = (const float*)d_in[6];
    const float* fc1w  = (const float*)d_in[7];
    const float* fc1b  = (const float*)d_in[8];
    const float* fc2w  = (const float*)d_in[9];
    const float* fc2b  = (const float*)d_in[10];
    float* out = (float*)d_out;

    const int N = in_sizes[0] / NFEAT;   // 50000
    const int E = in_sizes[2];           // 800000
    const int* row = eidx;
    const int* col = eidx + E;

    // workspace layout
    int*   icnt = (int*)d_ws;                  // N (padded 50176)
    int*   off  = icnt + 50176;                // N
    float* dis  = (float*)(off + 50176);       // N
    int*   bsum = (int*)(dis + 50176);         // 256
    int*   bpre = bsum + 256;                  // 256
    int2*  csr  = (int2*)(bpre + 256);         // E x 8B
    float* H    = (float*)(csr + E);           // N*64
    float* H2   = H + (size_t)N * 64;          // N*64

    const int TB = 256;
    int gN = (N + TB - 1) / TB;                // 196
    int gG = (N + 63) / 64;                    // 782
    int gA = (N * 64 + TB - 1) / TB;           // 12500
    int gE1 = (E + TB - 1) / TB;               // 3125
    int nb = gN;

    hipMemsetAsync(icnt, 0, (size_t)N * sizeof(int), stream);
    k_hist<<<1024, TB, 0, stream>>>(row, icnt, E);
    k_scanA<<<nb, TB, 0, stream>>>(icnt, bsum, N);
    k_scanB<<<1, TB, 0, stream>>>(bsum, bpre, nb);
    k_scanC<<<nb, TB, 0, stream>>>(icnt, bpre, off, dis, N);
    k_fill<<<gE1, TB, 0, stream>>>(row, col, eattr, dis, off, csr, E);

    // layer 1 GEMM
    k_gemm64<<<gG, TB, 0, stream>>>(x, W1, H, N);
    // agg1 + relu(.+b1)@W2 fused -> H2 (layer-2 features)
    k_agg_fused<<<2048, TB, 0, stream>>>(off, icnt, dis, csr, H, b1, W2, H2, N);
    // agg2 (plain, one wave/node) -> H holds conv2 pre-bias output
    k_agg<<<gA, TB, 0, stream>>>(off, icnt, dis, csr, H2, H, N);
    // MLP head (adds b2 inside)
    k_mlp<<<gG, TB, 0, stream>>>(H, b2, fc1w, fc1b, fc2w, fc2b, out, N);
}

// Round 9
// 282.075 us; speedup vs baseline: 1.0388x; 1.0188x over previous
//
#include <hip/hip_runtime.h>

// GCN forward: 2x GCNConv(64->64) + MLP(64->128->10), fp32, pull-based CSR.
// r9: r7 structure, but CSR-fill and gemm1 fused into ONE ordinary kernel
// (they are independent: fill needs off/dis, gemm needs x/W1 only). Scattered
// store latency overlaps FMA compute across co-resident blocks. No
// cooperative launch (r8's grid-residency validation failed silently).

#define NFEAT 64

// ---- CSR build ----------------------------------------------------------

__global__ void k_hist(const int* __restrict__ row, int* __restrict__ cnt, int ne) {
    int i = blockIdx.x * blockDim.x + threadIdx.x;
    int st = gridDim.x * blockDim.x;
    for (; i < ne; i += st) atomicAdd(&cnt[row[i]], 1);
}

__global__ void k_scanA(const int* __restrict__ cnt, int* __restrict__ bsum, int n) {
    __shared__ int s[256];
    int tid = threadIdx.x;
    int i = blockIdx.x * 256 + tid;
    s[tid] = (i < n) ? cnt[i] : 0;
    __syncthreads();
    for (int d = 128; d > 0; d >>= 1) {
        if (tid < d) s[tid] += s[tid + d];
        __syncthreads();
    }
    if (tid == 0) bsum[blockIdx.x] = s[0];
}

__global__ void k_scanB(const int* __restrict__ bsum, int* __restrict__ bpre, int nb) {
    __shared__ int s[256];
    int tid = threadIdx.x;
    int v = (tid < nb) ? bsum[tid] : 0;
    s[tid] = v;
    __syncthreads();
    for (int d = 1; d < 256; d <<= 1) {
        int t = (tid >= d) ? s[tid - d] : 0;
        __syncthreads();
        s[tid] += t;
        __syncthreads();
    }
    if (tid < nb) bpre[tid] = s[tid] - v;  // exclusive
}

// exclusive per-element offsets + dis = rsqrt(1+deg)
__global__ void k_scanC(const int* __restrict__ cnt, const int* __restrict__ bpre,
                        int* __restrict__ off, float* __restrict__ dis, int n) {
    __shared__ int s[256];
    int tid = threadIdx.x;
    int i = blockIdx.x * 256 + tid;
    int v = (i < n) ? cnt[i] : 0;
    s[tid] = v;
    __syncthreads();
    for (int d = 1; d < 256; d <<= 1) {
        int t = (tid >= d) ? s[tid - d] : 0;
        __syncthreads();
        s[tid] += t;
        __syncthreads();
    }
    if (i < n) {
        off[i] = bpre[blockIdx.x] + s[tid] - v;
        dis[i] = rsqrtf(1.0f + (float)v);
    }
}

// ---- fused CSR-fill + gemm1 ----------------------------------------------
// All blocks: grid-stride fill (scattered 8B stores; line-granular writeback
// is structural). Blocks < (N+63)/64 additionally compute one 64-row tile of
// H = x @ W1. Independent work; stores overlap FMAs across resident blocks.

__global__ __launch_bounds__(256, 4) void k_fill_gemm(const int* __restrict__ row,
                                                      const int* __restrict__ col,
                                                      const float* __restrict__ ew,
                                                      const float* __restrict__ dis,
                                                      int* __restrict__ off,
                                                      int2* __restrict__ csr,
                                                      const float* __restrict__ x,
                                                      const float* __restrict__ W1,
                                                      float* __restrict__ H,
                                                      int N, int E) {
    __shared__ float XT[64 * 68];
    __shared__ float Wl[64 * 64];
    int tid = threadIdx.x;
    int gtid = blockIdx.x * 256 + tid;
    int gstride = gridDim.x * 256;

    // fill slice (fire-and-forget scattered stores)
    for (int i = gtid; i < E; i += gstride) {
        int r = row[i], c = col[i];
        float w = dis[r] * ew[i] * dis[c];
        int slot = atomicAdd(&off[r], 1);
        csr[slot] = make_int2(c, __float_as_int(w));
    }

    // gemm tile
    int gG = (N + 63) >> 6;
    if (blockIdx.x >= gG) return;
    int r0 = blockIdx.x * 64;
    for (int i = tid; i < 64 * 64; i += 256) Wl[i] = W1[i];
    for (int i = tid; i < 64 * 64; i += 256) {
        int r = i >> 6, k = i & 63;
        int rr = r0 + r;
        XT[k * 68 + r] = (rr < N) ? x[(size_t)r0 * 64 + i] : 0.f;
    }
    __syncthreads();
    int f4 = (tid & 15) * 4;
    int r4 = (tid >> 4) * 4;
    float acc[4][4];
#pragma unroll
    for (int i = 0; i < 4; ++i)
#pragma unroll
        for (int j = 0; j < 4; ++j) acc[i][j] = 0.f;
#pragma unroll 8
    for (int k = 0; k < 64; ++k) {
        float4 w = *(const float4*)&Wl[k * 64 + f4];
        float4 xv = *(const float4*)&XT[k * 68 + r4];
        float xs[4] = {xv.x, xv.y, xv.z, xv.w};
        float ws[4] = {w.x, w.y, w.z, w.w};
#pragma unroll
        for (int i = 0; i < 4; ++i)
#pragma unroll
            for (int j = 0; j < 4; ++j) acc[i][j] = fmaf(xs[i], ws[j], acc[i][j]);
    }
#pragma unroll
    for (int i = 0; i < 4; ++i) {
        int rr = r0 + r4 + i;
        if (rr < N) {
            float4 o = make_float4(acc[i][0], acc[i][1], acc[i][2], acc[i][3]);
            *(float4*)&H[(size_t)rr * 64 + f4] = o;
        }
    }
}

// ---- agg core: returns aggregated quad (ALL lanes valid after reduce) ----

__device__ __forceinline__ float4 agg_row(const int* off_end, const int* cnt,
                                          const int2* csr, const float* H,
                                          int node, int sub, int q4) {
    int endv = off_end[node];
    int s = endv - cnt[node];
    float4 acc = make_float4(0.f, 0.f, 0.f, 0.f);
    int e = s + sub;
    for (; e + 4 < endv; e += 8) {
        int2 p0 = csr[e];
        int2 p1 = csr[e + 4];
        float w0 = __int_as_float(p0.y);
        float w1 = __int_as_float(p1.y);
        float4 h0 = *(const float4*)&H[(size_t)p0.x * 64 + q4];
        float4 h1 = *(const float4*)&H[(size_t)p1.x * 64 + q4];
        acc.x = fmaf(w0, h0.x, acc.x);
        acc.y = fmaf(w0, h0.y, acc.y);
        acc.z = fmaf(w0, h0.z, acc.z);
        acc.w = fmaf(w0, h0.w, acc.w);
        acc.x = fmaf(w1, h1.x, acc.x);
        acc.y = fmaf(w1, h1.y, acc.y);
        acc.z = fmaf(w1, h1.z, acc.z);
        acc.w = fmaf(w1, h1.w, acc.w);
    }
    if (e < endv) {
        int2 p = csr[e];
        float w = __int_as_float(p.y);
        float4 h = *(const float4*)&H[(size_t)p.x * 64 + q4];
        acc.x = fmaf(w, h.x, acc.x);
        acc.y = fmaf(w, h.y, acc.y);
        acc.z = fmaf(w, h.z, acc.z);
        acc.w = fmaf(w, h.w, acc.w);
    }
#pragma unroll
    for (int m = 16; m <= 32; m <<= 1) {
        acc.x += __shfl_xor(acc.x, m, 64);
        acc.y += __shfl_xor(acc.y, m, 64);
        acc.z += __shfl_xor(acc.z, m, 64);
        acc.w += __shfl_xor(acc.w, m, 64);
    }
    return acc;
}

// ---- plain agg (layer 2): AGG[i] = dis^2*H[i] + sum w*H[c] ---------------

__global__ __launch_bounds__(256) void k_agg(const int* __restrict__ off_end,
                                             const int* __restrict__ cnt,
                                             const float* __restrict__ dis,
                                             const int2* __restrict__ csr,
                                             const float* __restrict__ H,
                                             float* __restrict__ AGG, int n) {
    int l = threadIdx.x & 63;
    int node = (blockIdx.x * blockDim.x + threadIdx.x) >> 6;
    if (node >= n) return;
    int sub = l >> 4;
    int q4 = (l & 15) * 4;
    float4 acc = agg_row(off_end, cnt, csr, H, node, sub, q4);
    if (sub == 0) {
        float d = dis[node];
        float d2 = d * d;
        float4 hs = *(const float4*)&H[(size_t)node * 64 + q4];
        acc.x = fmaf(d2, hs.x, acc.x);
        acc.y = fmaf(d2, hs.y, acc.y);
        acc.z = fmaf(d2, hs.z, acc.z);
        acc.w = fmaf(d2, hs.w, acc.w);
        *(float4*)&AGG[(size_t)node * 64 + q4] = acc;
    }
}

// ---- fused agg1 + layer2 transform: H2 = relu(sym-agg(H1)+b1) @ W2 -------

__global__ __launch_bounds__(256) void k_agg_fused(const int* __restrict__ off_end,
                                                   const int* __restrict__ cnt,
                                                   const float* __restrict__ dis,
                                                   const int2* __restrict__ csr,
                                                   const float* __restrict__ H1,
                                                   const float* __restrict__ b1,
                                                   const float* __restrict__ W2,
                                                   float* __restrict__ H2, int n) {
    __shared__ float W2l[64 * 64];   // [k][f] 16KB
    __shared__ float pbuf[4][64];    // per-wave row buffer
    int tid = threadIdx.x;
    for (int i = tid; i < 64 * 64; i += 256) W2l[i] = W2[i];
    __syncthreads();
    int l = tid & 63;
    int wv = tid >> 6;
    int sub = l >> 4;
    int q4 = (l & 15) * 4;
    int nwaves = (gridDim.x * blockDim.x) >> 6;
    for (int node = (blockIdx.x * blockDim.x + tid) >> 6; node < n; node += nwaves) {
        float4 acc = agg_row(off_end, cnt, csr, H1, node, sub, q4);
        float d = dis[node];
        float d2 = d * d;
        float4 hs = *(const float4*)&H1[(size_t)node * 64 + q4];
        float4 bq = *(const float4*)&b1[q4];
        float4 p;
        p.x = fmaxf(fmaf(d2, hs.x, acc.x) + bq.x, 0.f);
        p.y = fmaxf(fmaf(d2, hs.y, acc.y) + bq.y, 0.f);
        p.z = fmaxf(fmaf(d2, hs.z, acc.z) + bq.z, 0.f);
        p.w = fmaxf(fmaf(d2, hs.w, acc.w) + bq.w, 0.f);
        if (sub == 0) *(float4*)&pbuf[wv][q4] = p;
        asm volatile("" ::: "memory");  // same-wave LDS is in-order
        float sum = 0.f;
#pragma unroll
        for (int q = 0; q < 16; ++q) {
            float4 v = *(const float4*)&pbuf[wv][q * 4];
            sum = fmaf(v.x, W2l[(q * 4 + 0) * 64 + l], sum);
            sum = fmaf(v.y, W2l[(q * 4 + 1) * 64 + l], sum);
            sum = fmaf(v.z, W2l[(q * 4 + 2) * 64 + l], sum);
            sum = fmaf(v.w, W2l[(q * 4 + 3) * 64 + l], sum);
        }
        asm volatile("" ::: "memory");
        H2[(size_t)node * 64 + l] = sum;
    }
}

// ---- fused MLP head: out = relu((AGG+b2)@fc1 + fc1b) @ fc2 + fc2b --------

__global__ __launch_bounds__(256, 4) void k_mlp(const float* __restrict__ AGG,
                                                const float* __restrict__ b2,
                                                const float* __restrict__ fc1w,
                                                const float* __restrict__ fc1b,
                                                const float* __restrict__ fc2w,
                                                const float* __restrict__ fc2b,
                                                float* __restrict__ out, int n) {
    __shared__ float XT[64 * 68];
    __shared__ float Wh[64 * 64];
    __shared__ float W2l[128 * 10];
    __shared__ float b1l[128];
    __shared__ float b2c[16];
    int tid = threadIdx.x;
    int r0 = blockIdx.x * 64;
    for (int i = tid; i < 64 * 64; i += 256) {
        int r = i >> 6, k = i & 63;
        int rr = r0 + r;
        float v = 0.f;
        if (rr < n) v = AGG[(size_t)r0 * 64 + i] + b2[k];
        XT[k * 68 + r] = v;
    }
    for (int i = tid; i < 64 * 64; i += 256)
        Wh[i] = fc1w[(i >> 6) * 128 + (i & 63)];
    for (int i = tid; i < 128 * 10; i += 256) W2l[i] = fc2w[i];
    if (tid < 128) b1l[tid] = fc1b[tid];
    if (tid < 10) b2c[tid] = fc2b[tid];
    float wreg[16];
#pragma unroll
    for (int i = 0; i < 16; ++i) {
        int idx = i * 256 + tid;
        wreg[i] = fc1w[(idx >> 6) * 128 + 64 + (idx & 63)];
    }
    __syncthreads();

    int f4 = (tid & 15) * 4;
    int r4 = (tid >> 4) * 4;
    float pacc[4][10];
#pragma unroll
    for (int i = 0; i < 4; ++i)
#pragma unroll
        for (int c = 0; c < 10; ++c) pacc[i][c] = 0.f;

#pragma unroll
    for (int h = 0; h < 2; ++h) {
        if (h == 1) {
            __syncthreads();
#pragma unroll
            for (int i = 0; i < 16; ++i) Wh[i * 256 + tid] = wreg[i];
            __syncthreads();
        }
        float acc[4][4];
#pragma unroll
        for (int i = 0; i < 4; ++i)
#pragma unroll
            for (int j = 0; j < 4; ++j) acc[i][j] = 0.f;
#pragma unroll 8
        for (int k = 0; k < 64; ++k) {
            float4 xv = *(const float4*)&XT[k * 68 + r4];
            float4 wv = *(const float4*)&Wh[k * 64 + f4];
            float xs[4] = {xv.x, xv.y, xv.z, xv.w};
            float ws[4] = {wv.x, wv.y, wv.z, wv.w};
#pragma unroll
            for (int i = 0; i < 4; ++i)
#pragma unroll
                for (int j = 0; j < 4; ++j) acc[i][j] = fmaf(xs[i], ws[j], acc[i][j]);
        }
#pragma unroll
        for (int jj = 0; jj < 4; ++jj) {
            int jcol = h * 64 + f4 + jj;
            float w2r[10];
#pragma unroll
            for (int c = 0; c < 10; ++c) w2r[c] = W2l[jcol * 10 + c];
            float bj = b1l[jcol];
#pragma unroll
            for (int i = 0; i < 4; ++i) {
                float pv = fmaxf(acc[i][jj] + bj, 0.f);
#pragma unroll
                for (int c = 0; c < 10; ++c) pacc[i][c] = fmaf(pv, w2r[c], pacc[i][c]);
            }
        }
    }
#pragma unroll
    for (int i = 0; i < 4; ++i)
#pragma unroll
        for (int c = 0; c < 10; ++c) {
            float v = pacc[i][c];
            v += __shfl_xor(v, 1, 64);
            v += __shfl_xor(v, 2, 64);
            v += __shfl_xor(v, 4, 64);
            v += __shfl_xor(v, 8, 64);
            pacc[i][c] = v;
        }
    if ((tid & 15) == 0) {
#pragma unroll
        for (int i = 0; i < 4; ++i) {
            int rr = r0 + r4 + i;
            if (rr < n) {
#pragma unroll
                for (int c = 0; c < 10; ++c)
                    out[(size_t)rr * 10 + c] = pacc[i][c] + b2c[c];
            }
        }
    }
}

// --------------------------------------------------------------------------

extern "C" void kernel_launch(void* const* d_in, const int* in_sizes, int n_in,
                              void* d_out, int out_size, void* d_ws, size_t ws_size,
                              hipStream_t stream) {
    const float* x     = (const float*)d_in[0];
    const int*   eidx  = (const int*)d_in[1];
    const float* eattr = (const float*)d_in[2];
    const float* W1    = (const float*)d_in[3];
    const float* b1    = (const float*)d_in[4];
    const float* W2    = (const float*)d_in[5];
    const float* b2    = (const float*)d_in[6];
    const float* fc1w  = (const float*)d_in[7];
    const float* fc1b  = (const float*)d_in[8];
    const float* fc2w  = (const float*)d_in[9];
    const float* fc2b  = (const float*)d_in[10];
    float* out = (float*)d_out;

    int N = in_sizes[0] / NFEAT;   // 50000
    int E = in_sizes[2];           // 800000
    const int* row = eidx;
    const int* col = eidx + E;

    // workspace layout
    int*   icnt = (int*)d_ws;                  // N (padded 50176)
    int*   off  = icnt + 50176;                // N
    float* dis  = (float*)(off + 50176);       // N
    int*   bsum = (int*)(dis + 50176);         // 256
    int*   bpre = bsum + 256;                  // 256
    int2*  csr  = (int2*)(bpre + 256);         // E x 8B
    float* H    = (float*)(csr + E);           // N*64
    float* H2   = H + (size_t)N * 64;          // N*64

    const int TB = 256;
    int gN = (N + TB - 1) / TB;                // 196
    int gG = (N + 63) / 64;                    // 782
    int gA = (N * 64 + TB - 1) / TB;           // 12500
    int nb = gN;

    hipMemsetAsync(icnt, 0, (size_t)N * sizeof(int), stream);
    k_hist<<<1024, TB, 0, stream>>>(row, icnt, E);
    k_scanA<<<nb, TB, 0, stream>>>(icnt, bsum, N);
    k_scanB<<<1, TB, 0, stream>>>(bsum, bpre, nb);
    k_scanC<<<nb, TB, 0, stream>>>(icnt, bpre, off, dis, N);

    // fused CSR fill + layer-1 GEMM (independent work, overlapped)
    k_fill_gemm<<<gG, TB, 0, stream>>>(row, col, eattr, dis, off, csr,
                                       x, W1, H, N, E);

    // agg1 + relu(.+b1)@W2 fused -> H2 (layer-2 features)
    k_agg_fused<<<2048, TB, 0, stream>>>(off, icnt, dis, csr, H, b1, W2, H2, N);
    // agg2 (plain, one wave/node) -> H holds conv2 pre-bias output
    k_agg<<<gA, TB, 0, stream>>>(off, icnt, dis, csr, H2, H, N);
    // MLP head (adds b2 inside)
    k_mlp<<<gG, TB, 0, stream>>>(H, b2, fc1w, fc1b, fc2w, fc2b, out, N);
}